// Round 1
// baseline (853.806 us; speedup 1.0000x reference)
//
#include <hip/hip_runtime.h>
#include <cmath>

#define B_  2048
#define N_  128
#define D_  64
#define H_  128

__device__ __forceinline__ void ld4(float* d, const float* s) {
  const float4 v = *(const float4*)s;
  d[0] = v.x; d[1] = v.y; d[2] = v.z; d[3] = v.w;
}
__device__ __forceinline__ void st4(float* d, const float* s) {
  *(float4*)d = make_float4(s[0], s[1], s[2], s[3]);
}

// Kernel A: per-node fused MLP + encoder.
//   h = x@W1[n] + b1[n]; h = LN(h)*g+b; h = gelu_exact(h);
//   p = h@W2[n] + b2[n]; m = p@encW + encb
// One block = node n x 64 batch rows. 256 threads, 4x4 register micro-tiles.
__global__ __launch_bounds__(256)
void k_mlp_enc(const float* __restrict__ xin, const float* __restrict__ W1,
               const float* __restrict__ b1, const float* __restrict__ lng,
               const float* __restrict__ lnb, const float* __restrict__ W2,
               const float* __restrict__ b2, const float* __restrict__ encW,
               const float* __restrict__ encb, float* __restrict__ mout) {
  __shared__ float xs[64][68];   // x tile; later reused as p tile (row stride 272B = 16B-aligned)
  __shared__ float hs[64][132];  // post-GELU h tile (row stride 528B = 16B-aligned)

  const int n  = blockIdx.y;
  const int b0 = blockIdx.x * 64;
  const int t  = threadIdx.x;

  // ---- phase 1: load x tile [64][64] ----
  {
    const int r = t >> 2, fq = t & 3;
    const float* src = xin + ((size_t)(b0 + r) * N_ + n) * D_;
    #pragma unroll
    for (int kk = 0; kk < 4; ++kk) {
      const int d4 = (fq * 4 + kk) * 4;
      *(float4*)&xs[r][d4] = *(const float4*)(src + d4);
    }
  }
  __syncthreads();

  // ---- phase 2: h = x@W1 + b1, then LN+GELU in-register ----
  // lanes: tj = j-tile (32 x 4 cols), tr = row-tile (8 x 4 rows); two row blocks (0..31, 32..63)
  {
    const int tj = t & 31, tr = t >> 5;
    const int j0 = tj * 4, r0 = tr * 4;

    float acc0[4][4], acc1[4][4];
    float b1v[4]; ld4(b1v, b1 + n * H_ + j0);
    #pragma unroll
    for (int k = 0; k < 4; ++k)
      #pragma unroll
      for (int jj = 0; jj < 4; ++jj) { acc0[k][jj] = b1v[jj]; acc1[k][jj] = b1v[jj]; }

    for (int d0 = 0; d0 < D_; d0 += 4) {
      float w[4][4];               // [dd][jj]
      #pragma unroll
      for (int dd = 0; dd < 4; ++dd) ld4(w[dd], W1 + ((size_t)(n * D_ + d0 + dd)) * H_ + j0);
      float xa[4][4], xb[4][4];    // [k][dd]
      #pragma unroll
      for (int k = 0; k < 4; ++k) { ld4(xa[k], &xs[r0 + k][d0]); ld4(xb[k], &xs[r0 + 32 + k][d0]); }
      #pragma unroll
      for (int k = 0; k < 4; ++k)
        #pragma unroll
        for (int dd = 0; dd < 4; ++dd)
          #pragma unroll
          for (int jj = 0; jj < 4; ++jj) {
            acc0[k][jj] = fmaf(xa[k][dd], w[dd][jj], acc0[k][jj]);
            acc1[k][jj] = fmaf(xb[k][dd], w[dd][jj], acc1[k][jj]);
          }
    }

    // LN + GELU. A row's 128 h-values live in the 32-lane half-wave sharing tr.
    float gv[4], bbv[4];
    ld4(gv,  lng + n * H_ + j0);
    ld4(bbv, lnb + n * H_ + j0);
    #pragma unroll
    for (int s = 0; s < 2; ++s) {
      float (*ac)[4] = s ? acc1 : acc0;
      #pragma unroll
      for (int k = 0; k < 4; ++k) {
        float sm = ac[k][0] + ac[k][1] + ac[k][2] + ac[k][3];
        float sq = ac[k][0]*ac[k][0] + ac[k][1]*ac[k][1] + ac[k][2]*ac[k][2] + ac[k][3]*ac[k][3];
        #pragma unroll
        for (int msk = 1; msk < 32; msk <<= 1) {
          sm += __shfl_xor(sm, msk);
          sq += __shfl_xor(sq, msk);
        }
        const float mu   = sm * (1.0f / H_);
        const float var  = sq * (1.0f / H_) - mu * mu;
        const float rstd = rsqrtf(var + 1e-5f);
        const int row = s * 32 + r0 + k;
        float out[4];
        #pragma unroll
        for (int jj = 0; jj < 4; ++jj) {
          const float v = (ac[k][jj] - mu) * rstd * gv[jj] + bbv[jj];
          out[jj] = 0.5f * v * (1.0f + erff(v * 0.70710678118654752f));
        }
        st4(&hs[row][j0], out);
      }
    }
  }
  __syncthreads();

  const int td = t & 15, tq = t >> 4;
  const int c0 = td * 4, pr0 = tq * 4;

  // ---- phase 3: p = h@W2 + b2 -> write into xs (reused as p tile) ----
  {
    float pacc[4][4];
    float b2v[4]; ld4(b2v, b2 + n * D_ + c0);
    #pragma unroll
    for (int k = 0; k < 4; ++k)
      #pragma unroll
      for (int c = 0; c < 4; ++c) pacc[k][c] = b2v[c];

    for (int j0 = 0; j0 < H_; j0 += 4) {
      float hv[4][4];  // [k][jj]
      #pragma unroll
      for (int k = 0; k < 4; ++k) ld4(hv[k], &hs[pr0 + k][j0]);
      float wv[4][4];  // [jj][c]
      #pragma unroll
      for (int jj = 0; jj < 4; ++jj) ld4(wv[jj], W2 + ((size_t)(n * H_ + j0 + jj)) * D_ + c0);
      #pragma unroll
      for (int k = 0; k < 4; ++k)
        #pragma unroll
        for (int jj = 0; jj < 4; ++jj)
          #pragma unroll
          for (int c = 0; c < 4; ++c)
            pacc[k][c] = fmaf(hv[k][jj], wv[jj][c], pacc[k][c]);
    }
    __syncthreads();                       // all xs (x-tile) reads finished long ago; safe
    #pragma unroll
    for (int k = 0; k < 4; ++k) st4(&xs[pr0 + k][c0], pacc[k]);
  }
  __syncthreads();

  // ---- phase 4: m = p@encW + encb -> global ----
  {
    float macc[4][4];
    float ebv[4]; ld4(ebv, encb + c0);
    #pragma unroll
    for (int k = 0; k < 4; ++k)
      #pragma unroll
      for (int c = 0; c < 4; ++c) macc[k][c] = ebv[c];

    for (int q0 = 0; q0 < D_; q0 += 4) {
      float pv[4][4];
      #pragma unroll
      for (int k = 0; k < 4; ++k) ld4(pv[k], &xs[pr0 + k][q0]);
      float ev[4][4];
      #pragma unroll
      for (int qq = 0; qq < 4; ++qq) ld4(ev[qq], encW + (q0 + qq) * D_ + c0);
      #pragma unroll
      for (int k = 0; k < 4; ++k)
        #pragma unroll
        for (int qq = 0; qq < 4; ++qq)
          #pragma unroll
          for (int c = 0; c < 4; ++c)
            macc[k][c] = fmaf(pv[k][qq], ev[qq][c], macc[k][c]);
    }
    #pragma unroll
    for (int k = 0; k < 4; ++k)
      st4(mout + ((size_t)(b0 + pr0 + k) * N_ + n) * D_ + c0, macc[k]);
  }
}

// Kernel B: connection aggregation + decoder.
//   r[b,i,:] = sum_j conn[i,j] * m[b,j,:];  x[b,i,:] = r@decW + decb
// One block = one batch element b. m[b] staged in LDS (32KB), reused as r buffer.
__global__ __launch_bounds__(256)
void k_conn_dec(const float* __restrict__ m, const float* __restrict__ conn,
                const float* __restrict__ decW, const float* __restrict__ decb,
                float* __restrict__ xout) {
  __shared__ float ms[128][68];
  const int b = blockIdx.x;
  const int t = threadIdx.x;

  // ---- load m[b] (contiguous 32KB) ----
  #pragma unroll
  for (int ii = 0; ii < 8; ++ii) {
    const int fidx = t + ii * 256;          // float4 index, 0..2047
    const int j = fidx >> 4, c = fidx & 15;
    *(float4*)&ms[j][c * 4] = *(const float4*)(m + ((size_t)b * N_ + j) * D_ + c * 4);
  }
  __syncthreads();

  const int te = t & 15, ti = t >> 4;
  const int e0 = te * 4, i0 = ti * 4;       // two i-blocks: i0 and i0+64

  // ---- r = conn @ ms ----
  float racc[2][4][4];
  #pragma unroll
  for (int s = 0; s < 2; ++s)
    #pragma unroll
    for (int k = 0; k < 4; ++k)
      #pragma unroll
      for (int c = 0; c < 4; ++c) racc[s][k][c] = 0.0f;

  for (int j0 = 0; j0 < N_; j0 += 4) {
    float cv[2][4][4];  // [s][k][jj]
    #pragma unroll
    for (int s = 0; s < 2; ++s)
      #pragma unroll
      for (int k = 0; k < 4; ++k) ld4(cv[s][k], conn + (size_t)(i0 + s * 64 + k) * N_ + j0);
    float mv[4][4];     // [jj][c]
    #pragma unroll
    for (int jj = 0; jj < 4; ++jj) ld4(mv[jj], &ms[j0 + jj][e0]);
    #pragma unroll
    for (int s = 0; s < 2; ++s)
      #pragma unroll
      for (int k = 0; k < 4; ++k)
        #pragma unroll
        for (int jj = 0; jj < 4; ++jj)
          #pragma unroll
          for (int c = 0; c < 4; ++c)
            racc[s][k][c] = fmaf(cv[s][k][jj], mv[jj][c], racc[s][k][c]);
  }
  __syncthreads();
  #pragma unroll
  for (int s = 0; s < 2; ++s)
    #pragma unroll
    for (int k = 0; k < 4; ++k) st4(&ms[i0 + s * 64 + k][e0], racc[s][k]);
  __syncthreads();

  // ---- x = r @ decW + decb ----
  float dbv[4]; ld4(dbv, decb + e0);
  float xacc[2][4][4];
  #pragma unroll
  for (int s = 0; s < 2; ++s)
    #pragma unroll
    for (int k = 0; k < 4; ++k)
      #pragma unroll
      for (int c = 0; c < 4; ++c) xacc[s][k][c] = dbv[c];

  for (int q0 = 0; q0 < D_; q0 += 4) {
    float rv[2][4][4];
    #pragma unroll
    for (int s = 0; s < 2; ++s)
      #pragma unroll
      for (int k = 0; k < 4; ++k) ld4(rv[s][k], &ms[i0 + s * 64 + k][q0]);
    float dv[4][4];
    #pragma unroll
    for (int qq = 0; qq < 4; ++qq) ld4(dv[qq], decW + (q0 + qq) * D_ + e0);
    #pragma unroll
    for (int s = 0; s < 2; ++s)
      #pragma unroll
      for (int k = 0; k < 4; ++k)
        #pragma unroll
        for (int qq = 0; qq < 4; ++qq)
          #pragma unroll
          for (int c = 0; c < 4; ++c)
            xacc[s][k][c] = fmaf(rv[s][k][qq], dv[qq][c], xacc[s][k][c]);
  }
  #pragma unroll
  for (int s = 0; s < 2; ++s)
    #pragma unroll
    for (int k = 0; k < 4; ++k)
      st4(xout + ((size_t)b * N_ + i0 + s * 64 + k) * D_ + e0, xacc[s][k]);
}

extern "C" void kernel_launch(void* const* d_in, const int* in_sizes, int n_in,
                              void* d_out, int out_size, void* d_ws, size_t ws_size,
                              hipStream_t stream) {
  const float* x0   = (const float*)d_in[0];
  const float* W1   = (const float*)d_in[1];
  const float* b1   = (const float*)d_in[2];
  const float* lng  = (const float*)d_in[3];
  const float* lnb  = (const float*)d_in[4];
  const float* W2   = (const float*)d_in[5];
  const float* b2   = (const float*)d_in[6];
  const float* encW = (const float*)d_in[7];
  const float* encb = (const float*)d_in[8];
  const float* decW = (const float*)d_in[9];
  const float* decb = (const float*)d_in[10];
  const float* conn = (const float*)d_in[11];

  float* xbuf = (float*)d_out;        // x ping-pongs through d_out
  float* mbuf = (float*)d_ws;         // m lives in workspace (needs 64MB)

  for (int d = 0; d < 3; ++d) {
    const float* xi = (d == 0) ? x0 : xbuf;
    k_mlp_enc<<<dim3(B_ / 64, N_), 256, 0, stream>>>(xi, W1, b1, lng, lnb, W2,
                                                     b2, encW, encb, mbuf);
    k_conn_dec<<<B_, 256, 0, stream>>>(mbuf, conn + (size_t)d * N_ * N_, decW,
                                       decb, xbuf);
  }
}

// Round 2
// 671.753 us; speedup vs baseline: 1.2710x; 1.2710x over previous
//
#include <hip/hip_runtime.h>
#include <cmath>

#define Bb 2048
#define Nn 128
#define Dd 64
#define Hh 128

typedef __attribute__((ext_vector_type(8))) short short8;
typedef __attribute__((ext_vector_type(4))) float f32x4;

__device__ __forceinline__ void ld4(float* d, const float* s) {
  const float4 v = *(const float4*)s;
  d[0] = v.x; d[1] = v.y; d[2] = v.z; d[3] = v.w;
}
__device__ __forceinline__ void st4(float* d, const float* s) {
  *(float4*)d = make_float4(s[0], s[1], s[2], s[3]);
}

__device__ __forceinline__ unsigned short f2bf(float f) {
  unsigned u = __float_as_uint(f);
  u += 0x7fffu + ((u >> 16) & 1u);       // RNE; NaN not expected in this workload
  return (unsigned short)(u >> 16);
}
__device__ __forceinline__ float bf2f(unsigned short h) {
  return __uint_as_float(((unsigned)h) << 16);
}
__device__ __forceinline__ void split2(float v, unsigned short& hi, unsigned short& lo) {
  hi = f2bf(v);
  lo = f2bf(v - bf2f(hi));
}

// ---------------------------------------------------------------------------
// Prep (once per launch): fold enc/dec into per-node weights, split to bf16
// hi/lo, and store TRANSPOSED for MFMA B-fragment loads.
//   E2 = encW @ decW                          [64][64]
//   Wfold[n] = W2[n] @ E2                     [128 h][64 f]
//   bfold[n] = b2[n] @ E2 + encb @ decW       [64]
//   W1t[n][col][k]  = W1[n][k][col]   (bf16 hi/lo)
//   Wft[n][f][h]    = Wfold[n][h][f]  (bf16 hi/lo)
// ---------------------------------------------------------------------------
__global__ __launch_bounds__(256)
void k_prep(const float* __restrict__ W1, const float* __restrict__ W2,
            const float* __restrict__ b2, const float* __restrict__ encW,
            const float* __restrict__ encb, const float* __restrict__ decW,
            unsigned short* __restrict__ W1tHi, unsigned short* __restrict__ W1tLo,
            unsigned short* __restrict__ WftHi, unsigned short* __restrict__ WftLo,
            float* __restrict__ bfold) {
  __shared__ float E2[64 * 64];
  __shared__ float decS[64 * 64];
  __shared__ unsigned bufC[64 * 65];   // pair staging, padded stride (bank-safe)
  const int n = blockIdx.x, t = threadIdx.x;

  // stage decW
  #pragma unroll
  for (int i = 0; i < 4; ++i)
    ((float4*)decS)[t + i * 256] = ((const float4*)decW)[t + i * 256];
  __syncthreads();

  // ebd[f] = encb @ decW (thread t<64 keeps its own f=t in a register)
  float ebd = 0.f;
  if (t < 64)
    for (int e = 0; e < 64; ++e) ebd += encb[e] * decS[e * 64 + t];

  // E2 = encW @ decW
  {
    const int d = t >> 2, f0 = (t & 3) * 16;
    float acc[16];
    #pragma unroll
    for (int ff = 0; ff < 16; ++ff) acc[ff] = 0.f;
    for (int e = 0; e < 64; ++e) {
      const float a = encW[d * 64 + e];
      #pragma unroll
      for (int ff = 0; ff < 16; ++ff) acc[ff] += a * decS[e * 64 + f0 + ff];
    }
    #pragma unroll
    for (int ff = 0; ff < 16; ++ff) E2[d * 64 + f0 + ff] = acc[ff];
  }
  __syncthreads();

  // bfold
  if (t < 64) {
    float s = ebd;
    for (int d2 = 0; d2 < 64; ++d2) s += b2[n * 64 + d2] * E2[d2 * 64 + t];
    bfold[n * 64 + t] = s;
  }

  // Wfold = W2[n] @ E2, split+transpose to Wft[f][h]
  for (int half = 0; half < 2; ++half) {
    const int h = half * 64 + (t >> 2), f0 = (t & 3) * 16;
    float acc[16];
    #pragma unroll
    for (int ff = 0; ff < 16; ++ff) acc[ff] = 0.f;
    for (int d2 = 0; d2 < 64; ++d2) {
      const float wv = W2[((size_t)n * 128 + h) * 64 + d2];
      #pragma unroll
      for (int ff = 0; ff < 16; ++ff) acc[ff] += wv * E2[d2 * 64 + f0 + ff];
    }
    #pragma unroll
    for (int ff = 0; ff < 16; ++ff) {
      unsigned short hi, lo; split2(acc[ff], hi, lo);
      bufC[(t >> 2) * 65 + f0 + ff] = ((unsigned)hi << 16) | lo;
    }
    __syncthreads();
    const int f = t >> 2, h0 = (t & 3) * 16;
    #pragma unroll
    for (int hh = 0; hh < 16; ++hh) {
      const unsigned pr = bufC[(h0 + hh) * 65 + f];
      const size_t o = ((size_t)n * 64 + f) * 128 + half * 64 + h0 + hh;
      WftHi[o] = (unsigned short)(pr >> 16);
      WftLo[o] = (unsigned short)(pr & 0xffffu);
    }
    __syncthreads();
  }

  // W1t[col][k] from W1[k][col], split bf16
  for (int half = 0; half < 2; ++half) {
    #pragma unroll
    for (int i = 0; i < 16; ++i) {
      const int li = t + i * 256;            // 0..4095
      const int d = li >> 6, c = li & 63;
      const float v = W1[((size_t)n * 64 + d) * 128 + half * 64 + c];
      unsigned short hi, lo; split2(v, hi, lo);
      bufC[d * 65 + c] = ((unsigned)hi << 16) | lo;
    }
    __syncthreads();
    const int c = t >> 2, d0 = (t & 3) * 16;
    #pragma unroll
    for (int dd = 0; dd < 16; ++dd) {
      const unsigned pr = bufC[(d0 + dd) * 65 + c];
      const size_t o = ((size_t)n * 128 + half * 64 + c) * 64 + d0 + dd;
      W1tHi[o] = (unsigned short)(pr >> 16);
      W1tLo[o] = (unsigned short)(pr & 0xffffu);
    }
    __syncthreads();
  }
}

// ---------------------------------------------------------------------------
// Kernel A: md[b,n,:] = GELU(LN(x@W1+b1)) @ Wfold[n] + bfold[n]
// MFMA 16x16x32 bf16 with 3-term hi/lo split (fp32-grade accuracy).
// Block = (64 batch rows) x (node n), 4 waves; wave w owns rows [16w,16w+16).
// ---------------------------------------------------------------------------
__global__ __launch_bounds__(256)
void k_mlp(const float* __restrict__ xin, const unsigned short* __restrict__ W1tHi,
           const unsigned short* __restrict__ W1tLo, const float* __restrict__ b1,
           const float* __restrict__ lng, const float* __restrict__ lnb,
           const unsigned short* __restrict__ WftHi, const unsigned short* __restrict__ WftLo,
           const float* __restrict__ bfold, float* __restrict__ md) {
  __shared__ unsigned short HgHi[64 * 128];   // XOR-swizzled: idx ^= (row&7)<<3
  __shared__ unsigned short HgLo[64 * 128];

  const int t = threadIdx.x;
  const int w = t >> 6, l = t & 63;
  const int lr = l & 15, lg = l >> 4, kb = lg * 8;
  const int n = blockIdx.y, b0 = blockIdx.x * 64;
  const int arow = w * 16 + lr;               // A-frag row (local)

  // ---- X A-fragments: direct global load + split ----
  short8 ahi[2], alo[2];
  {
    const float* xr = xin + ((size_t)(b0 + arow) * Nn + n) * Dd;
    #pragma unroll
    for (int c2 = 0; c2 < 2; ++c2) {
      const float4 p0 = *(const float4*)(xr + c2 * 32 + kb);
      const float4 p1 = *(const float4*)(xr + c2 * 32 + kb + 4);
      const float vv[8] = {p0.x, p0.y, p0.z, p0.w, p1.x, p1.y, p1.z, p1.w};
      #pragma unroll
      for (int j = 0; j < 8; ++j) {
        unsigned short hi, lo; split2(vv[j], hi, lo);
        ahi[c2][j] = (short)hi; alo[c2][j] = (short)lo;
      }
    }
  }

  // ---- GEMM1: h = x@W1 + b1 ----
  f32x4 acc[8];
  #pragma unroll
  for (int c = 0; c < 8; ++c) {
    const float bb = b1[n * Hh + c * 16 + lr];
    acc[c] = (f32x4){bb, bb, bb, bb};
  }
  {
    const unsigned short* wh = W1tHi + (size_t)n * Hh * Dd;
    const unsigned short* wl = W1tLo + (size_t)n * Hh * Dd;
    #pragma unroll
    for (int c = 0; c < 8; ++c) {
      const int col = c * 16 + lr;
      #pragma unroll
      for (int c2 = 0; c2 < 2; ++c2) {
        const short8 bh = *(const short8*)(wh + col * Dd + c2 * 32 + kb);
        const short8 bl = *(const short8*)(wl + col * Dd + c2 * 32 + kb);
        acc[c] = __builtin_amdgcn_mfma_f32_16x16x32_bf16(alo[c2], bh, acc[c], 0, 0, 0);
        acc[c] = __builtin_amdgcn_mfma_f32_16x16x32_bf16(ahi[c2], bl, acc[c], 0, 0, 0);
        acc[c] = __builtin_amdgcn_mfma_f32_16x16x32_bf16(ahi[c2], bh, acc[c], 0, 0, 0);
      }
    }
  }

  // ---- LayerNorm + exact GELU, split to bf16, write swizzled Hg ----
  {
    float mu[4], rs[4];
    #pragma unroll
    for (int r = 0; r < 4; ++r) {
      float sm = 0.f, sq = 0.f;
      #pragma unroll
      for (int c = 0; c < 8; ++c) { const float v = acc[c][r]; sm += v; sq += v * v; }
      #pragma unroll
      for (int msk = 1; msk < 16; msk <<= 1) {
        sm += __shfl_xor(sm, msk);
        sq += __shfl_xor(sq, msk);
      }
      mu[r] = sm * (1.f / Hh);
      const float var = sq * (1.f / Hh) - mu[r] * mu[r];
      rs[r] = rsqrtf(var + 1e-5f);
    }
    #pragma unroll
    for (int c = 0; c < 8; ++c) {
      const int col = c * 16 + lr;
      const float gv = lng[n * Hh + col], bv = lnb[n * Hh + col];
      #pragma unroll
      for (int r = 0; r < 4; ++r) {
        const int row = w * 16 + lg * 4 + r;
        float v = (acc[c][r] - mu[r]) * rs[r] * gv + bv;
        v = 0.5f * v * (1.f + erff(v * 0.70710678118654752440f));
        unsigned short hi, lo; split2(v, hi, lo);
        const int idx = (row * Hh + col) ^ ((row & 7) << 3);
        HgHi[idx] = hi; HgLo[idx] = lo;
      }
    }
  }
  __syncthreads();

  // ---- GEMM2: md = Hg @ Wfold + bfold ----
  f32x4 acc2[4];
  #pragma unroll
  for (int c = 0; c < 4; ++c) {
    const float bb = bfold[n * Dd + c * 16 + lr];
    acc2[c] = (f32x4){bb, bb, bb, bb};
  }
  short8 a2h[4], a2l[4];
  #pragma unroll
  for (int kc = 0; kc < 4; ++kc) {
    const int idx = (arow * Hh + kc * 32 + kb) ^ ((arow & 7) << 3);
    a2h[kc] = *(const short8*)&HgHi[idx];
    a2l[kc] = *(const short8*)&HgLo[idx];
  }
  {
    const unsigned short* wh = WftHi + (size_t)n * Dd * Hh;
    const unsigned short* wl = WftLo + (size_t)n * Dd * Hh;
    #pragma unroll
    for (int c = 0; c < 4; ++c) {
      const int f = c * 16 + lr;
      #pragma unroll
      for (int kc = 0; kc < 4; ++kc) {
        const short8 bh = *(const short8*)(wh + f * Hh + kc * 32 + kb);
        const short8 bl = *(const short8*)(wl + f * Hh + kc * 32 + kb);
        acc2[c] = __builtin_amdgcn_mfma_f32_16x16x32_bf16(a2l[kc], bh, acc2[c], 0, 0, 0);
        acc2[c] = __builtin_amdgcn_mfma_f32_16x16x32_bf16(a2h[kc], bl, acc2[c], 0, 0, 0);
        acc2[c] = __builtin_amdgcn_mfma_f32_16x16x32_bf16(a2h[kc], bh, acc2[c], 0, 0, 0);
      }
    }
  }
  #pragma unroll
  for (int c = 0; c < 4; ++c) {
    const int f = c * 16 + lr;
    #pragma unroll
    for (int r = 0; r < 4; ++r) {
      const int b = b0 + w * 16 + lg * 4 + r;
      md[((size_t)b * Nn + n) * Dd + f] = acc2[c][r];
    }
  }
}

// ---------------------------------------------------------------------------
// Kernel B: x[b,i,:] = sum_j conn[i,j]*md[b,j,:] + decb   (dec already folded)
// Memory-bound; proven VALU structure from round 1 (87% of HBM BW).
// ---------------------------------------------------------------------------
__global__ __launch_bounds__(256)
void k_conn(const float* __restrict__ md, const float* __restrict__ conn,
            const float* __restrict__ decb, float* __restrict__ xout) {
  __shared__ float ms[128][68];
  const int b = blockIdx.x;
  const int t = threadIdx.x;
  #pragma unroll
  for (int ii = 0; ii < 8; ++ii) {
    const int fidx = t + ii * 256;
    const int j = fidx >> 4, c = fidx & 15;
    *(float4*)&ms[j][c * 4] = *(const float4*)(md + ((size_t)b * Nn + j) * Dd + c * 4);
  }
  __syncthreads();

  const int te = t & 15, ti = t >> 4;
  const int e0 = te * 4, i0 = ti * 4;
  float db[4]; ld4(db, decb + e0);
  float racc[2][4][4];
  #pragma unroll
  for (int s = 0; s < 2; ++s)
    #pragma unroll
    for (int k = 0; k < 4; ++k)
      #pragma unroll
      for (int c = 0; c < 4; ++c) racc[s][k][c] = db[c];

  for (int j0 = 0; j0 < Nn; j0 += 4) {
    float cv[2][4][4];
    #pragma unroll
    for (int s = 0; s < 2; ++s)
      #pragma unroll
      for (int k = 0; k < 4; ++k) ld4(cv[s][k], conn + (size_t)(i0 + s * 64 + k) * Nn + j0);
    float mv[4][4];
    #pragma unroll
    for (int jj = 0; jj < 4; ++jj) ld4(mv[jj], &ms[j0 + jj][e0]);
    #pragma unroll
    for (int s = 0; s < 2; ++s)
      #pragma unroll
      for (int k = 0; k < 4; ++k)
        #pragma unroll
        for (int jj = 0; jj < 4; ++jj)
          #pragma unroll
          for (int c = 0; c < 4; ++c)
            racc[s][k][c] = fmaf(cv[s][k][jj], mv[jj][c], racc[s][k][c]);
  }
  #pragma unroll
  for (int s = 0; s < 2; ++s)
    #pragma unroll
    for (int k = 0; k < 4; ++k)
      st4(xout + ((size_t)b * Nn + i0 + s * 64 + k) * Dd + e0, racc[s][k]);
}

extern "C" void kernel_launch(void* const* d_in, const int* in_sizes, int n_in,
                              void* d_out, int out_size, void* d_ws, size_t ws_size,
                              hipStream_t stream) {
  const float* x0   = (const float*)d_in[0];
  const float* W1   = (const float*)d_in[1];
  const float* b1   = (const float*)d_in[2];
  const float* lng  = (const float*)d_in[3];
  const float* lnb  = (const float*)d_in[4];
  const float* W2   = (const float*)d_in[5];
  const float* b2   = (const float*)d_in[6];
  const float* encW = (const float*)d_in[7];
  const float* encb = (const float*)d_in[8];
  const float* decW = (const float*)d_in[9];
  const float* decb = (const float*)d_in[10];
  const float* conn = (const float*)d_in[11];

  char* ws = (char*)d_ws;
  float* md = (float*)ws;                                         // 64 MB
  unsigned short* W1tHi = (unsigned short*)(ws + (64ull << 20));  // 2 MB each
  unsigned short* W1tLo = W1tHi + (size_t)Nn * Hh * Dd;
  unsigned short* WftHi = W1tLo + (size_t)Nn * Hh * Dd;
  unsigned short* WftLo = WftHi + (size_t)Nn * Dd * Hh;
  float* bfold = (float*)(WftLo + (size_t)Nn * Dd * Hh);          // 32 KB
  // total ws use: 72 MB + 32 KB (flagged assumption: ws_size >= this)

  float* xbuf = (float*)d_out;

  k_prep<<<Nn, 256, 0, stream>>>(W1, W2, b2, encW, encb, decW,
                                 W1tHi, W1tLo, WftHi, WftLo, bfold);
  for (int d = 0; d < 3; ++d) {
    const float* xi = (d == 0) ? x0 : xbuf;
    k_mlp<<<dim3(Bb / 64, Nn), 256, 0, stream>>>(xi, W1tHi, W1tLo, b1, lng, lnb,
                                                 WftHi, WftLo, bfold, md);
    k_conn<<<Bb, 256, 0, stream>>>(md, conn + (size_t)d * Nn * Nn, decb, xbuf);
  }
}

// Round 3
// 473.718 us; speedup vs baseline: 1.8023x; 1.4180x over previous
//
#include <hip/hip_runtime.h>
#include <cmath>

#define Bb 2048
#define Nn 128
#define Dd 64
#define Hh 128

typedef __attribute__((ext_vector_type(8))) short short8;
typedef __attribute__((ext_vector_type(4))) float f32x4;

__device__ __forceinline__ void ld4(float* d, const float* s) {
  const float4 v = *(const float4*)s;
  d[0] = v.x; d[1] = v.y; d[2] = v.z; d[3] = v.w;
}
__device__ __forceinline__ void st4(float* d, const float* s) {
  *(float4*)d = make_float4(s[0], s[1], s[2], s[3]);
}

__device__ __forceinline__ unsigned short f2bf(float f) {
  unsigned u = __float_as_uint(f);
  u += 0x7fffu + ((u >> 16) & 1u);   // RNE
  return (unsigned short)(u >> 16);
}
__device__ __forceinline__ float bf2f(unsigned short h) {
  return __uint_as_float(((unsigned)h) << 16);
}
__device__ __forceinline__ void split2(float v, unsigned short& hi, unsigned short& lo) {
  hi = f2bf(v);
  lo = f2bf(v - bf2f(hi));
}

// ---------------------------------------------------------------------------
// k_e2 (1 block): E2 = encW @ decW  [64][64];  ebd = encb @ decW  [64]
// ---------------------------------------------------------------------------
__global__ __launch_bounds__(256)
void k_e2(const float* __restrict__ encW, const float* __restrict__ encb,
          const float* __restrict__ decW, float* __restrict__ E2,
          float* __restrict__ ebd) {
  __shared__ float decS[64 * 68];
  const int t = threadIdx.x;
  #pragma unroll
  for (int i = 0; i < 4; ++i) {
    const int fi = t + i * 256;            // float4 idx 0..1023
    const int e = fi >> 4, q = fi & 15;
    *(float4*)&decS[e * 68 + q * 4] = *(const float4*)(decW + fi * 4);
  }
  __syncthreads();

  if (t < 64) {
    float s = 0.f;
    for (int e = 0; e < 64; ++e) s += encb[e] * decS[e * 68 + t];
    ebd[t] = s;
  }
  {
    const int d = t >> 2, f0 = (t & 3) * 16;
    float acc[16];
    #pragma unroll
    for (int ff = 0; ff < 16; ++ff) acc[ff] = 0.f;
    for (int e = 0; e < 64; ++e) {
      const float a = encW[d * 64 + e];
      #pragma unroll
      for (int ff = 0; ff < 16; ++ff) acc[ff] += a * decS[e * 68 + f0 + ff];
    }
    #pragma unroll
    for (int q = 0; q < 4; ++q) st4(E2 + d * 64 + f0 + q * 4, &acc[q * 4]);
  }
}

// ---------------------------------------------------------------------------
// k_fold (grid Nn): Wfold[n] = W2[n] @ E2; bfold[n] = b2[n]@E2 + ebd;
// then fragment-pack Wfold into Wfp (hi/lo), per-lane MFMA-B order:
//   Wfp[n][c(4)][kc(4)][lane(64)][8],  f=c*16+(l&15), k=kc*32+(l>>4)*8+j
// ---------------------------------------------------------------------------
__global__ __launch_bounds__(256)
void k_fold(const float* __restrict__ W2, const float* __restrict__ b2,
            const float* __restrict__ E2, const float* __restrict__ ebd,
            unsigned short* __restrict__ WfpHi, unsigned short* __restrict__ WfpLo,
            float* __restrict__ bfold) {
  __shared__ float W2s[128 * 68];
  __shared__ float E2s[64 * 68];
  __shared__ float Wfs[128 * 68];
  const int n = blockIdx.x, t = threadIdx.x;

  #pragma unroll
  for (int i = 0; i < 8; ++i) {            // W2[n]: 2048 float4s
    const int fi = t + i * 256;
    const int h = fi >> 4, q = fi & 15;
    *(float4*)&W2s[h * 68 + q * 4] = *(const float4*)(W2 + (size_t)n * 8192 + fi * 4);
  }
  #pragma unroll
  for (int i = 0; i < 4; ++i) {            // E2: 1024 float4s
    const int fi = t + i * 256;
    const int d2 = fi >> 4, q = fi & 15;
    *(float4*)&E2s[d2 * 68 + q * 4] = *(const float4*)(E2 + fi * 4);
  }
  __syncthreads();

  if (t < 64) {
    float s = ebd[t];
    for (int d2 = 0; d2 < 64; ++d2) s += b2[n * 64 + d2] * E2s[d2 * 68 + t];
    bfold[n * 64 + t] = s;
  }
  {
    const int h = t >> 1, f0 = (t & 1) * 32;
    float acc[32];
    #pragma unroll
    for (int ff = 0; ff < 32; ++ff) acc[ff] = 0.f;
    for (int d2 = 0; d2 < 64; ++d2) {
      const float a = W2s[h * 68 + d2];
      #pragma unroll
      for (int q = 0; q < 8; ++q) {
        float e4[4]; ld4(e4, &E2s[d2 * 68 + f0 + q * 4]);
        #pragma unroll
        for (int r = 0; r < 4; ++r) acc[q * 4 + r] += a * e4[r];
      }
    }
    #pragma unroll
    for (int q = 0; q < 8; ++q) st4(&Wfs[h * 68 + f0 + q * 4], &acc[q * 4]);
  }
  __syncthreads();

  // pack: 1024 fragments-slots / 256 threads = 4 reps; coalesced 16B stores
  #pragma unroll
  for (int rep = 0; rep < 4; ++rep) {
    const int idx = rep * 256 + t;
    const int c = idx >> 8, kc = (idx >> 6) & 3, l = idx & 63;
    const int f = c * 16 + (l & 15), k0 = kc * 32 + (l >> 4) * 8;
    short8 vh, vl;
    #pragma unroll
    for (int j = 0; j < 8; ++j) {
      unsigned short hi, lo; split2(Wfs[(k0 + j) * 68 + f], hi, lo);
      vh[j] = (short)hi; vl[j] = (short)lo;
    }
    const size_t o = (((size_t)n * 4 + c) * 4 + kc) * 512 + (size_t)l * 8;
    *(short8*)(WfpHi + o) = vh;
    *(short8*)(WfpLo + o) = vl;
  }
}

// ---------------------------------------------------------------------------
// k_packW1 (grid Nn): fragment-pack W1 (hi/lo):
//   W1p[n][c(8)][c2(2)][lane(64)][8], col=c*16+(l&15), k=c2*32+(l>>4)*8+j
// ---------------------------------------------------------------------------
__global__ __launch_bounds__(256)
void k_packW1(const float* __restrict__ W1, unsigned short* __restrict__ W1pHi,
              unsigned short* __restrict__ W1pLo) {
  __shared__ float W1s[64 * 132];          // [d][col], pad 132
  const int n = blockIdx.x, t = threadIdx.x;
  #pragma unroll
  for (int i = 0; i < 8; ++i) {            // 2048 float4s
    const int fi = t + i * 256;
    const int d = fi >> 5, q = fi & 31;
    *(float4*)&W1s[d * 132 + q * 4] = *(const float4*)(W1 + (size_t)n * 8192 + fi * 4);
  }
  __syncthreads();
  #pragma unroll
  for (int rep = 0; rep < 4; ++rep) {
    const int idx = rep * 256 + t;
    const int c = idx >> 7, c2 = (idx >> 6) & 1, l = idx & 63;
    const int col = c * 16 + (l & 15), k0 = c2 * 32 + (l >> 4) * 8;
    short8 vh, vl;
    #pragma unroll
    for (int j = 0; j < 8; ++j) {
      unsigned short hi, lo; split2(W1s[(k0 + j) * 132 + col], hi, lo);
      vh[j] = (short)hi; vl[j] = (short)lo;
    }
    const size_t o = (((size_t)n * 8 + c) * 2 + c2) * 512 + (size_t)l * 8;
    *(short8*)(W1pHi + o) = vh;
    *(short8*)(W1pLo + o) = vl;
  }
}

// ---------------------------------------------------------------------------
// Kernel A: md[b,n,:] = GELU(LN(x@W1+b1)) @ Wfold[n] + bfold[n]
// B-fragments: coalesced loads from fragment-packed weights.
// Grid: 4096 blocks, XCD-bijective swizzle (16 contiguous nodes per XCD).
// ---------------------------------------------------------------------------
__global__ __launch_bounds__(256)
void k_mlp(const float* __restrict__ xin, const unsigned short* __restrict__ W1pHi,
           const unsigned short* __restrict__ W1pLo, const float* __restrict__ b1,
           const float* __restrict__ lng, const float* __restrict__ lnb,
           const unsigned short* __restrict__ WfpHi, const unsigned short* __restrict__ WfpLo,
           const float* __restrict__ bfold, float* __restrict__ md) {
  __shared__ unsigned short HgHi[64 * 128];   // XOR-swizzled: idx ^= (row&7)<<3
  __shared__ unsigned short HgLo[64 * 128];

  const int t = threadIdx.x;
  const int w = t >> 6, l = t & 63;
  const int lr = l & 15, lg = l >> 4, kb = lg * 8;
  // XCD-bijective block swizzle: 4096 blocks, 8 XCDs -> 16 nodes/XCD
  const int wg = blockIdx.x;
  const int n  = (wg & 7) * 16 + ((wg >> 3) >> 5);
  const int b0 = ((wg >> 3) & 31) * 64;
  const int arow = w * 16 + lr;

  // ---- X A-fragments: coalesced global float4 + split ----
  short8 ahi[2], alo[2];
  {
    const float* xr = xin + ((size_t)(b0 + arow) * Nn + n) * Dd;
    #pragma unroll
    for (int c2 = 0; c2 < 2; ++c2) {
      const float4 p0 = *(const float4*)(xr + c2 * 32 + kb);
      const float4 p1 = *(const float4*)(xr + c2 * 32 + kb + 4);
      const float vv[8] = {p0.x, p0.y, p0.z, p0.w, p1.x, p1.y, p1.z, p1.w};
      #pragma unroll
      for (int j = 0; j < 8; ++j) {
        unsigned short hi, lo; split2(vv[j], hi, lo);
        ahi[c2][j] = (short)hi; alo[c2][j] = (short)lo;
      }
    }
  }

  // ---- GEMM1: h = x@W1 + b1 (3-term split bf16 MFMA) ----
  f32x4 acc[8];
  #pragma unroll
  for (int c = 0; c < 8; ++c) {
    const float bb = b1[n * Hh + c * 16 + lr];
    acc[c] = (f32x4){bb, bb, bb, bb};
  }
  {
    const unsigned short* wh = W1pHi + (size_t)n * 8192 + (size_t)l * 8;
    const unsigned short* wl = W1pLo + (size_t)n * 8192 + (size_t)l * 8;
    #pragma unroll
    for (int c = 0; c < 8; ++c) {
      #pragma unroll
      for (int c2 = 0; c2 < 2; ++c2) {
        const int fo = (c * 2 + c2) * 512;
        const short8 bh = *(const short8*)(wh + fo);
        const short8 bl = *(const short8*)(wl + fo);
        acc[c] = __builtin_amdgcn_mfma_f32_16x16x32_bf16(alo[c2], bh, acc[c], 0, 0, 0);
        acc[c] = __builtin_amdgcn_mfma_f32_16x16x32_bf16(ahi[c2], bl, acc[c], 0, 0, 0);
        acc[c] = __builtin_amdgcn_mfma_f32_16x16x32_bf16(ahi[c2], bh, acc[c], 0, 0, 0);
      }
    }
  }

  // ---- LayerNorm + exact GELU, split to bf16, write swizzled Hg ----
  {
    float mu[4], rs[4];
    #pragma unroll
    for (int r = 0; r < 4; ++r) {
      float sm = 0.f, sq = 0.f;
      #pragma unroll
      for (int c = 0; c < 8; ++c) { const float v = acc[c][r]; sm += v; sq += v * v; }
      #pragma unroll
      for (int msk = 1; msk < 16; msk <<= 1) {
        sm += __shfl_xor(sm, msk);
        sq += __shfl_xor(sq, msk);
      }
      mu[r] = sm * (1.f / Hh);
      const float var = sq * (1.f / Hh) - mu[r] * mu[r];
      rs[r] = rsqrtf(var + 1e-5f);
    }
    #pragma unroll
    for (int c = 0; c < 8; ++c) {
      const int col = c * 16 + lr;
      const float gv = lng[n * Hh + col], bv = lnb[n * Hh + col];
      #pragma unroll
      for (int r = 0; r < 4; ++r) {
        const int row = w * 16 + lg * 4 + r;
        float v = (acc[c][r] - mu[r]) * rs[r] * gv + bv;
        v = 0.5f * v * (1.f + erff(v * 0.70710678118654752440f));
        unsigned short hi, lo; split2(v, hi, lo);
        const int idx = (row * Hh + col) ^ ((row & 7) << 3);
        HgHi[idx] = hi; HgLo[idx] = lo;
      }
    }
  }
  __syncthreads();

  // ---- GEMM2: md = Hg @ Wfold + bfold ----
  f32x4 acc2[4];
  #pragma unroll
  for (int c = 0; c < 4; ++c) {
    const float bb = bfold[n * Dd + c * 16 + lr];
    acc2[c] = (f32x4){bb, bb, bb, bb};
  }
  short8 a2h[4], a2l[4];
  #pragma unroll
  for (int kc = 0; kc < 4; ++kc) {
    const int idx = (arow * Hh + kc * 32 + kb) ^ ((arow & 7) << 3);
    a2h[kc] = *(const short8*)&HgHi[idx];
    a2l[kc] = *(const short8*)&HgLo[idx];
  }
  {
    const unsigned short* fh = WfpHi + (size_t)n * 8192 + (size_t)l * 8;
    const unsigned short* fl = WfpLo + (size_t)n * 8192 + (size_t)l * 8;
    #pragma unroll
    for (int c = 0; c < 4; ++c) {
      #pragma unroll
      for (int kc = 0; kc < 4; ++kc) {
        const int fo = (c * 4 + kc) * 512;
        const short8 bh = *(const short8*)(fh + fo);
        const short8 bl = *(const short8*)(fl + fo);
        acc2[c] = __builtin_amdgcn_mfma_f32_16x16x32_bf16(a2l[kc], bh, acc2[c], 0, 0, 0);
        acc2[c] = __builtin_amdgcn_mfma_f32_16x16x32_bf16(a2h[kc], bl, acc2[c], 0, 0, 0);
        acc2[c] = __builtin_amdgcn_mfma_f32_16x16x32_bf16(a2h[kc], bh, acc2[c], 0, 0, 0);
      }
    }
  }
  #pragma unroll
  for (int c = 0; c < 4; ++c) {
    const int f = c * 16 + lr;
    #pragma unroll
    for (int r = 0; r < 4; ++r) {
      const int b = b0 + w * 16 + lg * 4 + r;
      md[((size_t)b * Nn + n) * Dd + f] = acc2[c][r];
    }
  }
}

// ---------------------------------------------------------------------------
// Kernel B: x[b,i,:] = sum_j conn[i,j]*md[b,j,:] + decb   (dec folded away)
// ---------------------------------------------------------------------------
__global__ __launch_bounds__(256)
void k_conn(const float* __restrict__ md, const float* __restrict__ conn,
            const float* __restrict__ decb, float* __restrict__ xout) {
  __shared__ float ms[128][68];
  const int b = blockIdx.x;
  const int t = threadIdx.x;
  #pragma unroll
  for (int ii = 0; ii < 8; ++ii) {
    const int fidx = t + ii * 256;
    const int j = fidx >> 4, c = fidx & 15;
    *(float4*)&ms[j][c * 4] = *(const float4*)(md + ((size_t)b * Nn + j) * Dd + c * 4);
  }
  __syncthreads();

  const int te = t & 15, ti = t >> 4;
  const int e0 = te * 4, i0 = ti * 4;
  float db[4]; ld4(db, decb + e0);
  float racc[2][4][4];
  #pragma unroll
  for (int s = 0; s < 2; ++s)
    #pragma unroll
    for (int k = 0; k < 4; ++k)
      #pragma unroll
      for (int c = 0; c < 4; ++c) racc[s][k][c] = db[c];

  for (int j0 = 0; j0 < Nn; j0 += 4) {
    float cv[2][4][4];
    #pragma unroll
    for (int s = 0; s < 2; ++s)
      #pragma unroll
      for (int k = 0; k < 4; ++k) ld4(cv[s][k], conn + (size_t)(i0 + s * 64 + k) * Nn + j0);
    float mv[4][4];
    #pragma unroll
    for (int jj = 0; jj < 4; ++jj) ld4(mv[jj], &ms[j0 + jj][e0]);
    #pragma unroll
    for (int s = 0; s < 2; ++s)
      #pragma unroll
      for (int k = 0; k < 4; ++k)
        #pragma unroll
        for (int jj = 0; jj < 4; ++jj)
          #pragma unroll
          for (int c = 0; c < 4; ++c)
            racc[s][k][c] = fmaf(cv[s][k][jj], mv[jj][c], racc[s][k][c]);
  }
  #pragma unroll
  for (int s = 0; s < 2; ++s)
    #pragma unroll
    for (int k = 0; k < 4; ++k)
      st4(xout + ((size_t)b * Nn + i0 + s * 64 + k) * Dd + e0, racc[s][k]);
}

extern "C" void kernel_launch(void* const* d_in, const int* in_sizes, int n_in,
                              void* d_out, int out_size, void* d_ws, size_t ws_size,
                              hipStream_t stream) {
  const float* x0   = (const float*)d_in[0];
  const float* W1   = (const float*)d_in[1];
  const float* b1   = (const float*)d_in[2];
  const float* lng  = (const float*)d_in[3];
  const float* lnb  = (const float*)d_in[4];
  const float* W2   = (const float*)d_in[5];
  const float* b2   = (const float*)d_in[6];
  const float* encW = (const float*)d_in[7];
  const float* encb = (const float*)d_in[8];
  const float* decW = (const float*)d_in[9];
  const float* decb = (const float*)d_in[10];
  const float* conn = (const float*)d_in[11];

  char* ws = (char*)d_ws;
  float* md = (float*)ws;                               // 64 MB
  size_t off = 64ull << 20;
  unsigned short* W1pHi = (unsigned short*)(ws + off); off += 2ull << 20;
  unsigned short* W1pLo = (unsigned short*)(ws + off); off += 2ull << 20;
  unsigned short* WfpHi = (unsigned short*)(ws + off); off += 2ull << 20;
  unsigned short* WfpLo = (unsigned short*)(ws + off); off += 2ull << 20;
  float* bfold = (float*)(ws + off); off += 128 * 64 * 4;
  float* E2    = (float*)(ws + off); off += 64 * 64 * 4;
  float* ebd   = (float*)(ws + off); off += 64 * 4;

  float* xbuf = (float*)d_out;

  k_e2<<<1, 256, 0, stream>>>(encW, encb, decW, E2, ebd);
  k_packW1<<<Nn, 256, 0, stream>>>(W1, W1pHi, W1pLo);
  k_fold<<<Nn, 256, 0, stream>>>(W2, b2, E2, ebd, WfpHi, WfpLo, bfold);
  for (int d = 0; d < 3; ++d) {
    const float* xi = (d == 0) ? x0 : xbuf;
    k_mlp<<<4096, 256, 0, stream>>>(xi, W1pHi, W1pLo, b1, lng, lnb,
                                    WfpHi, WfpLo, bfold, md);
    k_conn<<<Bb, 256, 0, stream>>>(md, conn + (size_t)d * Nn * Nn, decb, xbuf);
  }
}

// Round 4
// 431.843 us; speedup vs baseline: 1.9771x; 1.0970x over previous
//
#include <hip/hip_runtime.h>
#include <cmath>

#define Bb 2048
#define Nn 128
#define Dd 64
#define Hh 128

typedef __attribute__((ext_vector_type(8))) short short8;
typedef __attribute__((ext_vector_type(4))) float f32x4;

__device__ __forceinline__ void ld4(float* d, const float* s) {
  const float4 v = *(const float4*)s;
  d[0] = v.x; d[1] = v.y; d[2] = v.z; d[3] = v.w;
}
__device__ __forceinline__ void st4(float* d, const float* s) {
  *(float4*)d = make_float4(s[0], s[1], s[2], s[3]);
}

// Fast 2-way bf16 split: hi = round-half-up bf16 (half-ulp, 2^-9 rel),
// lo = truncated bf16 of residual (2^-17 rel total). Dropped lo*lo MFMA term
// is ~2^-18 rel -> same accuracy class as RNE split at ~half the VALU ops.
__device__ __forceinline__ void splitf(float v, unsigned short& hi, unsigned short& lo) {
  const unsigned up = __float_as_uint(v) + 0x8000u;
  hi = (unsigned short)(up >> 16);
  const float hif = __uint_as_float(up & 0xffff0000u);
  lo = (unsigned short)(__float_as_uint(v - hif) >> 16);
}

// Branch-free exact-GELU via Abramowitz-Stegun 7.1.26 (|erf err| <= 1.5e-7).
__device__ __forceinline__ float gelu_exact(float v) {
  const float s  = fabsf(v) * 0.70710678118654752f;
  const float tt = __builtin_amdgcn_rcpf(fmaf(0.3275911f, s, 1.0f));
  float p = fmaf(tt, 1.061405429f, -1.453152027f);
  p = fmaf(tt, p, 1.421413741f);
  p = fmaf(tt, p, -0.284496736f);
  p = fmaf(tt, p, 0.254829592f);
  p = p * tt;
  const float E  = exp2f(s * s * -1.44269504088896f);
  const float er = fmaf(-p, E, 1.0f);          // erf(|v|/sqrt(2))
  const float es = copysignf(er, v);
  return v * fmaf(0.5f, es, 0.5f);
}

// ---------------------------------------------------------------------------
// k_prep (grid Nn, one launch): per block n —
//   E2 = encW@decW (redundant per block, cheap);  bfold[n] = b2[n]@E2 + encb@decW
//   Wfold[n] = W2[n]@E2 -> fragment-pack hi/lo:  Wfp[n][c4][kc4][lane][8]
//   W1[n] -> fragment-pack hi/lo:                W1p[n][c8][c2][lane][8]
//   colpack[n][col] = float4(b1, lng, lnb, 0)
// LDS phase-overlaid: decS|E2s overlaid later by W1s. 104KB total.
// ---------------------------------------------------------------------------
__global__ __launch_bounds__(256)
void k_prep(const float* __restrict__ W1, const float* __restrict__ b1,
            const float* __restrict__ lng, const float* __restrict__ lnb,
            const float* __restrict__ W2, const float* __restrict__ b2,
            const float* __restrict__ encW, const float* __restrict__ encb,
            const float* __restrict__ decW,
            unsigned short* __restrict__ W1pHi, unsigned short* __restrict__ W1pLo,
            unsigned short* __restrict__ WfpHi, unsigned short* __restrict__ WfpLo,
            float* __restrict__ bfold, float4* __restrict__ colpack) {
  __shared__ float sm[26112];                  // 104.4 KB
  float* decS = sm;                            // [64][68]
  float* E2s  = sm + 4352;                     // [64][68]
  float* W2s  = sm + 8704;                     // [128][68]
  float* Wfs  = sm + 17408;                    // [128][68]
  float* W1s  = sm;                            // [64][132] overlays decS+E2s
  const int n = blockIdx.x, t = threadIdx.x;

  // phase 1: stage decW, W2[n]
  #pragma unroll
  for (int i = 0; i < 4; ++i) {
    const int fi = t + i * 256;
    *(float4*)&decS[(fi >> 4) * 68 + (fi & 15) * 4] = *(const float4*)(decW + fi * 4);
  }
  #pragma unroll
  for (int i = 0; i < 8; ++i) {
    const int fi = t + i * 256;
    *(float4*)&W2s[(fi >> 4) * 68 + (fi & 15) * 4] =
        *(const float4*)(W2 + (size_t)n * 8192 + fi * 4);
  }
  __syncthreads();

  // phase 2: E2 = encW @ decW
  {
    const int d = t >> 2, f0 = (t & 3) * 16;
    float acc[16];
    #pragma unroll
    for (int ff = 0; ff < 16; ++ff) acc[ff] = 0.f;
    for (int e = 0; e < 64; ++e) {
      const float a = encW[d * 64 + e];
      #pragma unroll
      for (int ff = 0; ff < 16; ++ff) acc[ff] += a * decS[e * 68 + f0 + ff];
    }
    #pragma unroll
    for (int q = 0; q < 4; ++q) st4(&E2s[d * 68 + f0 + q * 4], &acc[q * 4]);
  }
  __syncthreads();

  // phase 3: Wfs = W2s @ E2s; bfold; colpack
  {
    const int h = t >> 1, f0 = (t & 1) * 32;
    float acc[32];
    #pragma unroll
    for (int ff = 0; ff < 32; ++ff) acc[ff] = 0.f;
    for (int d2 = 0; d2 < 64; ++d2) {
      const float a = W2s[h * 68 + d2];
      #pragma unroll
      for (int q = 0; q < 8; ++q) {
        float e4[4]; ld4(e4, &E2s[d2 * 68 + f0 + q * 4]);
        #pragma unroll
        for (int r = 0; r < 4; ++r) acc[q * 4 + r] += a * e4[r];
      }
    }
    #pragma unroll
    for (int q = 0; q < 8; ++q) st4(&Wfs[h * 68 + f0 + q * 4], &acc[q * 4]);
  }
  if (t < 64) {
    float s = 0.f;
    for (int e = 0; e < 64; ++e) s += encb[e] * decS[e * 68 + t];
    for (int d2 = 0; d2 < 64; ++d2) s += b2[n * 64 + d2] * E2s[d2 * 68 + t];
    bfold[n * 64 + t] = s;
  }
  if (t < 128)
    colpack[n * 128 + t] =
        make_float4(b1[n * 128 + t], lng[n * 128 + t], lnb[n * 128 + t], 0.f);
  __syncthreads();

  // phase 4: pack Wfs -> Wfp; stage W1 -> W1s (disjoint LDS regions)
  #pragma unroll
  for (int rep = 0; rep < 4; ++rep) {
    const int idx = rep * 256 + t;
    const int c = idx >> 8, kc = (idx >> 6) & 3, l = idx & 63;
    const int f = c * 16 + (l & 15), k0 = kc * 32 + (l >> 4) * 8;
    short8 vh, vl;
    #pragma unroll
    for (int j = 0; j < 8; ++j) {
      unsigned short hi, lo; splitf(Wfs[(k0 + j) * 68 + f], hi, lo);
      vh[j] = (short)hi; vl[j] = (short)lo;
    }
    const size_t o = (((size_t)n * 4 + c) * 4 + kc) * 512 + (size_t)l * 8;
    *(short8*)(WfpHi + o) = vh;
    *(short8*)(WfpLo + o) = vl;
  }
  #pragma unroll
  for (int i = 0; i < 8; ++i) {
    const int fi = t + i * 256;
    *(float4*)&W1s[(fi >> 5) * 132 + (fi & 31) * 4] =
        *(const float4*)(W1 + (size_t)n * 8192 + fi * 4);
  }
  __syncthreads();

  // phase 5: pack W1s -> W1p
  #pragma unroll
  for (int rep = 0; rep < 4; ++rep) {
    const int idx = rep * 256 + t;
    const int c = idx >> 7, c2 = (idx >> 6) & 1, l = idx & 63;
    const int col = c * 16 + (l & 15), k0 = c2 * 32 + (l >> 4) * 8;
    short8 vh, vl;
    #pragma unroll
    for (int j = 0; j < 8; ++j) {
      unsigned short hi, lo; splitf(W1s[(k0 + j) * 132 + col], hi, lo);
      vh[j] = (short)hi; vl[j] = (short)lo;
    }
    const size_t o = (((size_t)n * 8 + c) * 2 + c2) * 512 + (size_t)l * 8;
    *(short8*)(W1pHi + o) = vh;
    *(short8*)(W1pLo + o) = vl;
  }
}

// ---------------------------------------------------------------------------
// Kernel A: md[b,n,:] = GELU(LN(x@W1+b1)) @ Wfold[n] + bfold[n]
// ---------------------------------------------------------------------------
__global__ __launch_bounds__(256)
void k_mlp(const float* __restrict__ xin, const unsigned short* __restrict__ W1pHi,
           const unsigned short* __restrict__ W1pLo,
           const float4* __restrict__ colpack,
           const unsigned short* __restrict__ WfpHi, const unsigned short* __restrict__ WfpLo,
           const float* __restrict__ bfold, float* __restrict__ md) {
  __shared__ unsigned short HgHi[64 * 128];   // XOR-swizzled: idx ^= (row&7)<<3
  __shared__ unsigned short HgLo[64 * 128];

  const int t = threadIdx.x;
  const int w = t >> 6, l = t & 63;
  const int lr = l & 15, lg = l >> 4, kb = lg * 8;
  // XCD-bijective block swizzle: 4096 blocks, 8 XCDs -> 16 contiguous nodes/XCD
  const int wg = blockIdx.x;
  const int n  = (wg & 7) * 16 + ((wg >> 3) >> 5);
  const int b0 = ((wg >> 3) & 31) * 64;
  const int arow = w * 16 + lr;

  // ---- X A-fragments: coalesced global float4 + fast split ----
  short8 ahi[2], alo[2];
  {
    const float* xr = xin + ((size_t)(b0 + arow) * Nn + n) * Dd;
    #pragma unroll
    for (int c2 = 0; c2 < 2; ++c2) {
      const float4 p0 = *(const float4*)(xr + c2 * 32 + kb);
      const float4 p1 = *(const float4*)(xr + c2 * 32 + kb + 4);
      const float vv[8] = {p0.x, p0.y, p0.z, p0.w, p1.x, p1.y, p1.z, p1.w};
      #pragma unroll
      for (int j = 0; j < 8; ++j) {
        unsigned short hi, lo; splitf(vv[j], hi, lo);
        ahi[c2][j] = (short)hi; alo[c2][j] = (short)lo;
      }
    }
  }

  // ---- per-column constants (b1, ln_g, ln_b) as packed float4 ----
  float4 cpv[8];
  #pragma unroll
  for (int c = 0; c < 8; ++c) cpv[c] = colpack[n * 128 + c * 16 + lr];

  // ---- GEMM1: h = x@W1 + b1 (3-term split bf16 MFMA) ----
  f32x4 acc[8];
  #pragma unroll
  for (int c = 0; c < 8; ++c) {
    const float bb = cpv[c].x;
    acc[c] = (f32x4){bb, bb, bb, bb};
  }
  {
    const unsigned short* wh = W1pHi + (size_t)n * 8192 + (size_t)l * 8;
    const unsigned short* wl = W1pLo + (size_t)n * 8192 + (size_t)l * 8;
    #pragma unroll
    for (int c = 0; c < 8; ++c) {
      #pragma unroll
      for (int c2 = 0; c2 < 2; ++c2) {
        const int fo = (c * 2 + c2) * 512;
        const short8 bh = *(const short8*)(wh + fo);
        const short8 bl = *(const short8*)(wl + fo);
        acc[c] = __builtin_amdgcn_mfma_f32_16x16x32_bf16(alo[c2], bh, acc[c], 0, 0, 0);
        acc[c] = __builtin_amdgcn_mfma_f32_16x16x32_bf16(ahi[c2], bl, acc[c], 0, 0, 0);
        acc[c] = __builtin_amdgcn_mfma_f32_16x16x32_bf16(ahi[c2], bh, acc[c], 0, 0, 0);
      }
    }
  }

  // ---- LayerNorm + GELU, split to bf16, write swizzled Hg ----
  {
    float mu[4], rs[4];
    #pragma unroll
    for (int r = 0; r < 4; ++r) {
      float sm = 0.f, sq = 0.f;
      #pragma unroll
      for (int c = 0; c < 8; ++c) { const float v = acc[c][r]; sm += v; sq += v * v; }
      #pragma unroll
      for (int msk = 1; msk < 16; msk <<= 1) {
        sm += __shfl_xor(sm, msk);
        sq += __shfl_xor(sq, msk);
      }
      mu[r] = sm * (1.f / Hh);
      const float var = sq * (1.f / Hh) - mu[r] * mu[r];
      rs[r] = rsqrtf(var + 1e-5f);
    }
    #pragma unroll
    for (int c = 0; c < 8; ++c) {
      const int col = c * 16 + lr;
      const float gv = cpv[c].y, bv = cpv[c].z;
      #pragma unroll
      for (int r = 0; r < 4; ++r) {
        const int row = w * 16 + lg * 4 + r;
        const float v = gelu_exact((acc[c][r] - mu[r]) * rs[r] * gv + bv);
        unsigned short hi, lo; splitf(v, hi, lo);
        const int idx = (row * Hh + col) ^ ((row & 7) << 3);
        HgHi[idx] = hi; HgLo[idx] = lo;
      }
    }
  }
  __syncthreads();

  // ---- GEMM2: md = Hg @ Wfold + bfold ----
  f32x4 acc2[4];
  #pragma unroll
  for (int c = 0; c < 4; ++c) {
    const float bb = bfold[n * Dd + c * 16 + lr];
    acc2[c] = (f32x4){bb, bb, bb, bb};
  }
  short8 a2h[4], a2l[4];
  #pragma unroll
  for (int kc = 0; kc < 4; ++kc) {
    const int idx = (arow * Hh + kc * 32 + kb) ^ ((arow & 7) << 3);
    a2h[kc] = *(const short8*)&HgHi[idx];
    a2l[kc] = *(const short8*)&HgLo[idx];
  }
  {
    const unsigned short* fh = WfpHi + (size_t)n * 8192 + (size_t)l * 8;
    const unsigned short* fl = WfpLo + (size_t)n * 8192 + (size_t)l * 8;
    #pragma unroll
    for (int c = 0; c < 4; ++c) {
      #pragma unroll
      for (int kc = 0; kc < 4; ++kc) {
        const int fo = (c * 4 + kc) * 512;
        const short8 bh = *(const short8*)(fh + fo);
        const short8 bl = *(const short8*)(fl + fo);
        acc2[c] = __builtin_amdgcn_mfma_f32_16x16x32_bf16(a2l[kc], bh, acc2[c], 0, 0, 0);
        acc2[c] = __builtin_amdgcn_mfma_f32_16x16x32_bf16(a2h[kc], bl, acc2[c], 0, 0, 0);
        acc2[c] = __builtin_amdgcn_mfma_f32_16x16x32_bf16(a2h[kc], bh, acc2[c], 0, 0, 0);
      }
    }
  }
  #pragma unroll
  for (int c = 0; c < 4; ++c) {
    const int f = c * 16 + lr;
    #pragma unroll
    for (int r = 0; r < 4; ++r) {
      const int b = b0 + w * 16 + lg * 4 + r;
      md[((size_t)b * Nn + n) * Dd + f] = acc2[c][r];
    }
  }
}

// ---------------------------------------------------------------------------
// Kernel B: x[b,i,:] = sum_j conn[i,j]*md[b,j,:] + decb   (dec folded away)
// ---------------------------------------------------------------------------
__global__ __launch_bounds__(256)
void k_conn(const float* __restrict__ md, const float* __restrict__ conn,
            const float* __restrict__ decb, float* __restrict__ xout) {
  __shared__ float ms[128][68];
  const int b = blockIdx.x;
  const int t = threadIdx.x;
  #pragma unroll
  for (int ii = 0; ii < 8; ++ii) {
    const int fidx = t + ii * 256;
    const int j = fidx >> 4, c = fidx & 15;
    *(float4*)&ms[j][c * 4] = *(const float4*)(md + ((size_t)b * Nn + j) * Dd + c * 4);
  }
  __syncthreads();

  const int te = t & 15, ti = t >> 4;
  const int e0 = te * 4, i0 = ti * 4;
  float db[4]; ld4(db, decb + e0);
  float racc[2][4][4];
  #pragma unroll
  for (int s = 0; s < 2; ++s)
    #pragma unroll
    for (int k = 0; k < 4; ++k)
      #pragma unroll
      for (int c = 0; c < 4; ++c) racc[s][k][c] = db[c];

  for (int j0 = 0; j0 < Nn; j0 += 4) {
    float cv[2][4][4];
    #pragma unroll
    for (int s = 0; s < 2; ++s)
      #pragma unroll
      for (int k = 0; k < 4; ++k) ld4(cv[s][k], conn + (size_t)(i0 + s * 64 + k) * Nn + j0);
    float mv[4][4];
    #pragma unroll
    for (int jj = 0; jj < 4; ++jj) ld4(mv[jj], &ms[j0 + jj][e0]);
    #pragma unroll
    for (int s = 0; s < 2; ++s)
      #pragma unroll
      for (int k = 0; k < 4; ++k)
        #pragma unroll
        for (int jj = 0; jj < 4; ++jj)
          #pragma unroll
          for (int c = 0; c < 4; ++c)
            racc[s][k][c] = fmaf(cv[s][k][jj], mv[jj][c], racc[s][k][c]);
  }
  #pragma unroll
  for (int s = 0; s < 2; ++s)
    #pragma unroll
    for (int k = 0; k < 4; ++k)
      st4(xout + ((size_t)b * Nn + i0 + s * 64 + k) * Dd + e0, racc[s][k]);
}

extern "C" void kernel_launch(void* const* d_in, const int* in_sizes, int n_in,
                              void* d_out, int out_size, void* d_ws, size_t ws_size,
                              hipStream_t stream) {
  const float* x0   = (const float*)d_in[0];
  const float* W1   = (const float*)d_in[1];
  const float* b1   = (const float*)d_in[2];
  const float* lng  = (const float*)d_in[3];
  const float* lnb  = (const float*)d_in[4];
  const float* W2   = (const float*)d_in[5];
  const float* b2   = (const float*)d_in[6];
  const float* encW = (const float*)d_in[7];
  const float* encb = (const float*)d_in[8];
  const float* decW = (const float*)d_in[9];
  const float* decb = (const float*)d_in[10];
  const float* conn = (const float*)d_in[11];

  char* ws = (char*)d_ws;
  float* md = (float*)ws;                               // 64 MB
  size_t off = 64ull << 20;
  unsigned short* W1pHi = (unsigned short*)(ws + off); off += 2ull << 20;
  unsigned short* W1pLo = (unsigned short*)(ws + off); off += 2ull << 20;
  unsigned short* WfpHi = (unsigned short*)(ws + off); off += 2ull << 20;
  unsigned short* WfpLo = (unsigned short*)(ws + off); off += 2ull << 20;
  float* bfold    = (float*)(ws + off); off += 128 * 64 * 4;
  float4* colpack = (float4*)(ws + off); off += 128 * 128 * 16;

  float* xbuf = (float*)d_out;

  k_prep<<<Nn, 256, 0, stream>>>(W1, b1, lng, lnb, W2, b2, encW, encb, decW,
                                 W1pHi, W1pLo, WfpHi, WfpLo, bfold, colpack);
  for (int d = 0; d < 3; ++d) {
    const float* xi = (d == 0) ? x0 : xbuf;
    k_mlp<<<4096, 256, 0, stream>>>(xi, W1pHi, W1pLo, colpack,
                                    WfpHi, WfpLo, bfold, md);
    k_conn<<<Bb, 256, 0, stream>>>(md, conn + (size_t)d * Nn * Nn, decb, xbuf);
  }
}